// Round 2
// baseline (1388.568 us; speedup 1.0000x reference)
//
#include <hip/hip_runtime.h>
#include <hip/hip_bf16.h>
#include <math.h>

#define N_NODES 10000
#define N_EDGES 640000
#define DDIM 256
#define NBLK_E 2500   // N_EDGES / 256 exactly

typedef long long i64;

__device__ __forceinline__ float sigmoidf_(float x) { return 1.0f / (1.0f + expf(-x)); }

// ---------------- encoder: h = relu([emb|feat] @ W_enc + b_enc) ----------------
__global__ __launch_bounds__(256) void encode_kernel(
    const float* __restrict__ feat, const float* __restrict__ emb,
    const float* __restrict__ W, const float* __restrict__ b, float* __restrict__ h)
{
    const int n = blockIdx.x;
    const int t = threadIdx.x;
    __shared__ float in_s[40];
    if (t < 32) in_s[t] = emb[(i64)n * 32 + t];
    else if (t < 40) in_s[t] = feat[(i64)n * 8 + (t - 32)];
    __syncthreads();
    float acc = b[t];
#pragma unroll
    for (int k = 0; k < 40; ++k) acc += in_s[k] * W[k * DDIM + t];
    h[(i64)n * DDIM + t] = fmaxf(acc, 0.0f);
}

// ---------------- fused GEMM: C = epi(A1@W1 [+ A2@W2] + bias) ----------------
enum { EPI_NONE = 0, EPI_TANH, EPI_SIGM, EPI_RH, EPI_HOUT, EPI_RELU };

template<int EPI, bool DUAL>
__global__ __launch_bounds__(256) void gemm_epi(
    const float* __restrict__ A1, const float* __restrict__ W1,
    const float* __restrict__ A2, const float* __restrict__ W2,
    const float* __restrict__ bias,
    const float* __restrict__ haux, const float* __restrict__ zaux,
    float* __restrict__ C)
{
    __shared__ __align__(16) float As[16][68];   // [k][row]; stride 68 floats = 272B = 17*16B (float4-aligned, conflict-light)
    __shared__ __align__(16) float Bs[16][64];   // [k][col]
    const int tid = threadIdx.x;
    const int tx = tid & 15;       // col group (4 cols each)
    const int ty = tid >> 4;       // row group (4 rows each)
    const int brow = blockIdx.x * 64;
    const int bcol = blockIdx.y * 64;

    const int lrow = tid >> 2;          // 0..63
    const int lk4  = (tid & 3) << 2;    // 0,4,8,12
    const int wkrow = tid >> 4;         // 0..15
    const int wcol4 = (tid & 15) << 2;  // 0..60

    const int arow = brow + lrow;
    const bool arow_ok = (arow < N_NODES);
    const i64 aoff = (i64)(arow_ok ? arow : 0) * DDIM;

    float acc[4][4] = {{0.f,0.f,0.f,0.f},{0.f,0.f,0.f,0.f},{0.f,0.f,0.f,0.f},{0.f,0.f,0.f,0.f}};

    for (int pass = 0; pass < (DUAL ? 2 : 1); ++pass) {
        const float* Ap = (pass ? A2 : A1) + aoff;
        const float* Wp = (pass ? W2 : W1);
        for (int k0 = 0; k0 < DDIM; k0 += 16) {
            float4 av = arow_ok ? *(const float4*)(Ap + k0 + lk4) : make_float4(0.f,0.f,0.f,0.f);
            float4 wv = *(const float4*)(Wp + (i64)(k0 + wkrow) * DDIM + bcol + wcol4);
            __syncthreads();
            As[lk4+0][lrow] = av.x; As[lk4+1][lrow] = av.y;
            As[lk4+2][lrow] = av.z; As[lk4+3][lrow] = av.w;
            *(float4*)&Bs[wkrow][wcol4] = wv;
            __syncthreads();
#pragma unroll
            for (int k = 0; k < 16; ++k) {
                float4 a = *(const float4*)&As[k][ty << 2];
                float4 b = *(const float4*)&Bs[k][tx << 2];
                acc[0][0] += a.x*b.x; acc[0][1] += a.x*b.y; acc[0][2] += a.x*b.z; acc[0][3] += a.x*b.w;
                acc[1][0] += a.y*b.x; acc[1][1] += a.y*b.y; acc[1][2] += a.y*b.z; acc[1][3] += a.y*b.w;
                acc[2][0] += a.z*b.x; acc[2][1] += a.z*b.y; acc[2][2] += a.z*b.z; acc[2][3] += a.z*b.w;
                acc[3][0] += a.w*b.x; acc[3][1] += a.w*b.y; acc[3][2] += a.w*b.z; acc[3][3] += a.w*b.w;
            }
        }
    }

#pragma unroll
    for (int i = 0; i < 4; ++i) {
        const int r = brow + (ty << 2) + i;
        if (r < N_NODES) {
#pragma unroll
            for (int j = 0; j < 4; ++j) {
                const int c = bcol + (tx << 2) + j;
                const i64 idx = (i64)r * DDIM + c;
                float v = acc[i][j];
                float out;
                if constexpr (EPI == EPI_NONE)      out = v;
                else if constexpr (EPI == EPI_TANH) out = tanhf(v + bias[c]);
                else if constexpr (EPI == EPI_SIGM) out = sigmoidf_(v + bias[c]);
                else if constexpr (EPI == EPI_RH)   out = sigmoidf_(v + bias[c]) * haux[idx];
                else if constexpr (EPI == EPI_HOUT) {
                    float cand = tanhf(v + bias[c]);
                    float zz = zaux[idx];
                    out = zz * haux[idx] + (1.0f - zz) * cand;
                } else                               out = fmaxf(v + bias[c], 0.0f);
                C[idx] = out;
            }
        }
    }
}

// ---------------- agg[n,:] = sum over out-edges of node n (src-sorted CSR) of t[dst[e],:] ----------------
__global__ __launch_bounds__(256) void agg_kernel(
    const float* __restrict__ t, const int* __restrict__ dst, const int* __restrict__ rp,
    float* __restrict__ agg)
{
    const int n = blockIdx.x;
    const int d = threadIdx.x;
    const int s = rp[n], e = rp[n + 1];
    float a0 = 0.f, a1 = 0.f, a2 = 0.f, a3 = 0.f;
    int i = s;
    for (; i + 4 <= e; i += 4) {
        int d0 = dst[i], d1 = dst[i+1], d2 = dst[i+2], d3 = dst[i+3];
        a0 += t[(i64)d0 * DDIM + d];
        a1 += t[(i64)d1 * DDIM + d];
        a2 += t[(i64)d2 * DDIM + d];
        a3 += t[(i64)d3 * DDIM + d];
    }
    for (; i < e; ++i) a0 += t[(i64)dst[i] * DDIM + d];
    agg[(i64)n * DDIM + d] = (a0 + a1) + (a2 + a3);
}

// ---------------- W_dec [256,N] -> wdt [N,256] ----------------
__global__ __launch_bounds__(256) void transpose_kernel(
    const float* __restrict__ Wd, float* __restrict__ wdt)
{
    __shared__ float tile[32][33];
    const int bx = blockIdx.x;  // over N
    const int by = blockIdx.y;  // over 256
    const int tx = threadIdx.x & 31, ty = threadIdx.x >> 5; // 32x8
#pragma unroll
    for (int j = 0; j < 4; ++j) {
        int k = by * 32 + ty + j * 8;
        int nc = bx * 32 + tx;
        if (nc < N_NODES) tile[ty + j * 8][tx] = Wd[(i64)k * N_NODES + nc];
    }
    __syncthreads();
#pragma unroll
    for (int j = 0; j < 4; ++j) {
        int nr = bx * 32 + ty + j * 8;
        int k = by * 32 + tx;
        if (nr < N_NODES) wdt[(i64)nr * DDIM + k] = tile[tx][ty + j * 8];
    }
}

// ---------------- per-src-node: logits (h[n]·wdt[dst]+b_dec[dst]) then segment softmax ----------------
__global__ __launch_bounds__(256) void logits_softmax_kernel(
    const float* __restrict__ h, const float* __restrict__ wdt,
    const float* __restrict__ b_dec, const int* __restrict__ dst,
    const int* __restrict__ rp, float* __restrict__ w)
{
    const int n = blockIdx.x;
    const int s = rp[n], e = rp[n + 1];
    const int tid = threadIdx.x;
    const int lane = tid & 63, wv = tid >> 6;
    __shared__ __align__(16) float hs[256];
    __shared__ float sred[8];
    hs[tid] = h[(i64)n * DDIM + tid];
    __syncthreads();
    float4 hv = ((const float4*)hs)[lane];
    for (int i = s + wv; i < e; i += 4) {   // uniform per wave
        const int dd = dst[i];
        float4 a = *(const float4*)(wdt + (i64)dd * DDIM + (lane << 2));
        float p = a.x*hv.x + a.y*hv.y + a.z*hv.z + a.w*hv.w;
#pragma unroll
        for (int o = 32; o; o >>= 1) p += __shfl_down(p, o);
        if (lane == 0) w[i] = p + b_dec[dd];
    }
    __syncthreads();
    if (e <= s) return;  // uniform per block (no divergent barrier)
    // max
    float m = -INFINITY;
    for (int i = s + tid; i < e; i += 256) m = fmaxf(m, w[i]);
#pragma unroll
    for (int o = 32; o; o >>= 1) m = fmaxf(m, __shfl_down(m, o));
    if (lane == 0) sred[wv] = m;
    __syncthreads();
    m = fmaxf(fmaxf(sred[0], sred[1]), fmaxf(sred[2], sred[3]));
    // exp + sum
    float ss = 0.f;
    for (int i = s + tid; i < e; i += 256) { float ev = expf(w[i] - m); w[i] = ev; ss += ev; }
#pragma unroll
    for (int o = 32; o; o >>= 1) ss += __shfl_down(ss, o);
    if (lane == 0) sred[4 + wv] = ss;
    __syncthreads();
    ss = (sred[4] + sred[5]) + (sred[6] + sred[7]);
    float inv = 1.0f / ss;
    for (int i = s + tid; i < e; i += 256) w[i] *= inv;
}

// ---------------- misc small kernels ----------------
__global__ void zero_misc_kernel(int* __restrict__ cnt, float* __restrict__ red) {
    int i = blockIdx.x * 256 + threadIdx.x;
    if (i < N_NODES) cnt[i] = 0;
    if (i < 8) red[i] = 0.0f;
}

__global__ void rowptr_kernel(const int* __restrict__ key, int* __restrict__ rp) {
    int n = blockIdx.x * 256 + threadIdx.x;
    if (n > N_NODES) return;
    int lo = 0, hi = N_EDGES;
    while (lo < hi) { int mid = (lo + hi) >> 1; if (key[mid] < n) lo = mid + 1; else hi = mid; }
    rp[n] = lo;
}

__global__ void hist_kernel(const int* __restrict__ dst, int* __restrict__ cnt) {
    int e = blockIdx.x * 256 + threadIdx.x;
    atomicAdd(&cnt[dst[e]], 1);
}

__global__ __launch_bounds__(256) void scan_kernel(int* __restrict__ cnt, int* __restrict__ rp) {
    __shared__ int part[256];
    const int t = threadIdx.x;
    const int chunk = (N_NODES + 255) / 256;
    int b = t * chunk, en = min(b + chunk, N_NODES);
    int s = 0;
    for (int i = b; i < en; ++i) s += cnt[i];
    part[t] = s;
    __syncthreads();
    for (int o = 1; o < 256; o <<= 1) {
        int v = (t >= o) ? part[t - o] : 0;
        __syncthreads();
        part[t] += v;
        __syncthreads();
    }
    int base = (t == 0) ? 0 : part[t - 1];
    for (int i = b; i < en; ++i) { rp[i] = base; base += cnt[i]; cnt[i] = 0; }
    if (t == 255) rp[N_NODES] = part[255];
}

__global__ void scatter_kernel(const int* __restrict__ src, const int* __restrict__ dst,
                               const float* __restrict__ w, const int* __restrict__ rp_d,
                               int* __restrict__ cnt, int* __restrict__ sp, float* __restrict__ wp)
{
    int e = blockIdx.x * 256 + threadIdx.x;
    int dd = dst[e];
    int pos = rp_d[dd] + atomicAdd(&cnt[dd], 1);
    sp[pos] = src[e];
    wp[pos] = w[e];
}

__global__ void init_adj_kernel(const float* __restrict__ dem, float* __restrict__ adjA) {
    int n = blockIdx.x * 256 + threadIdx.x;
    if (n < N_NODES) adjA[n] = fmaxf(-dem[n], 0.0f);
}

// adj_new[n] = relu( sum_{incoming edges of n} wp[i]*adj_old[sp[i]] - d[n] )
__global__ __launch_bounds__(256) void flow_iter_kernel(
    const float* __restrict__ wp, const int* __restrict__ sp, const int* __restrict__ rp_d,
    const float* __restrict__ adj_old, const float* __restrict__ dem, float* __restrict__ adj_new)
{
    const int n = blockIdx.x * 4 + (threadIdx.x >> 6);
    if (n >= N_NODES) return;
    const int lane = threadIdx.x & 63;
    const int s = rp_d[n], e = rp_d[n + 1];
    float acc = 0.f;
    for (int i = s + lane; i < e; i += 64) acc += wp[i] * adj_old[sp[i]];
#pragma unroll
    for (int o = 32; o; o >>= 1) acc += __shfl_down(acc, o);
    if (lane == 0) adj_new[n] = fmaxf(acc - dem[n], 0.0f);
}

__global__ __launch_bounds__(256) void flow_out_kernel(
    const float* __restrict__ w, const int* __restrict__ src, const float* __restrict__ adj,
    float* __restrict__ out_flow, float* __restrict__ red)
{
    __shared__ float sred[4];
    int e = blockIdx.x * 256 + threadIdx.x;
    float f = w[e] * adj[src[e]];
    out_flow[e] = f;
    float p = f * f;
#pragma unroll
    for (int o = 32; o; o >>= 1) p += __shfl_down(p, o);
    int lane = threadIdx.x & 63, wv = threadIdx.x >> 6;
    if (lane == 0) sred[wv] = p;
    __syncthreads();
    if (threadIdx.x == 0) atomicAdd(&red[0], (sred[0] + sred[1]) + (sred[2] + sred[3]));
}

// dv[n] = relu-head output; one wave per node; ONE atomic per block (contention fix)
__global__ __launch_bounds__(256) void dv_kernel(
    const float* __restrict__ t2, const float* __restrict__ Wd2, const float* __restrict__ bd2,
    const float* __restrict__ dem, float* __restrict__ dv, float* __restrict__ red)
{
    __shared__ float sred[4];
    const int n = blockIdx.x * 4 + (threadIdx.x >> 6);
    const int lane = threadIdx.x & 63, wv = threadIdx.x >> 6;
    float contrib = 0.0f;
    if (n < N_NODES) {
        float4 a = *(const float4*)(t2 + (i64)n * DDIM + (lane << 2));
        float4 b = *(const float4*)(Wd2 + (lane << 2));
        float p = a.x*b.x + a.y*b.y + a.z*b.z + a.w*b.w;
#pragma unroll
        for (int o = 32; o; o >>= 1) p += __shfl_down(p, o);
        if (lane == 0) {
            float v = p + bd2[0];
            dv[n] = v;
            contrib = v * dem[n];
        }
    }
    if (lane == 0) sred[wv] = contrib;
    __syncthreads();
    if (threadIdx.x == 0) atomicAdd(&red[2], (sred[0] + sred[1]) + (sred[2] + sred[3]));
}

__global__ __launch_bounds__(256) void dual_edge_kernel(
    const float* __restrict__ dv, const int* __restrict__ src, const int* __restrict__ dst,
    float* __restrict__ red)
{
    __shared__ float sred[4];
    int e = blockIdx.x * 256 + threadIdx.x;
    float df = dv[src[e]] - dv[dst[e]];
    float f = fmaxf(df * 0.5f, 0.0f);
    float val = f * f - f * df;
#pragma unroll
    for (int o = 32; o; o >>= 1) val += __shfl_down(val, o);
    int lane = threadIdx.x & 63, wv = threadIdx.x >> 6;
    if (lane == 0) sred[wv] = val;
    __syncthreads();
    if (threadIdx.x == 0) atomicAdd(&red[1], (sred[0] + sred[1]) + (sred[2] + sred[3]));
}

__global__ void finalize_kernel(const float* __restrict__ red, float* __restrict__ out) {
    // loss = flow_cost - dual_cost = red0 - (red1 - red2) = red0 - red1 + red2
    out[0] = red[0] - red[1] + red[2];
}

// ---------------- launch ----------------
extern "C" void kernel_launch(void* const* d_in, const int* in_sizes, int n_in,
                              void* d_out, int out_size, void* d_ws, size_t ws_size,
                              hipStream_t stream) {
    (void)in_sizes; (void)n_in; (void)out_size; (void)ws_size;
    const float* feat   = (const float*)d_in[0];
    const float* emb    = (const float*)d_in[1];
    const float* dem    = (const float*)d_in[2];
    const int*   e_src  = (const int*)d_in[3];
    const int*   e_dst  = (const int*)d_in[4];
    const float* W_enc  = (const float*)d_in[5];
    const float* b_enc  = (const float*)d_in[6];
    const float* W_ai   = (const float*)d_in[7];
    const float* W_ao   = (const float*)d_in[8];
    const float* b_agg  = (const float*)d_in[9];
    const float* W_z    = (const float*)d_in[10];
    const float* U_z    = (const float*)d_in[11];
    const float* b_z    = (const float*)d_in[12];
    const float* W_r    = (const float*)d_in[13];
    const float* U_r    = (const float*)d_in[14];
    const float* b_r    = (const float*)d_in[15];
    const float* W_h    = (const float*)d_in[16];
    const float* U_h    = (const float*)d_in[17];
    const float* b_h    = (const float*)d_in[18];
    const float* W_dec  = (const float*)d_in[19];
    const float* b_dec  = (const float*)d_in[20];
    const float* W_d1   = (const float*)d_in[21];
    const float* b_d1   = (const float*)d_in[22];
    const float* W_d2   = (const float*)d_in[23];
    const float* b_d2   = (const float*)d_in[24];

    float* ws = (float*)d_ws;
    const size_t F = (size_t)N_NODES * DDIM;
    float* h    = ws;            // [N,256]
    float* t    = ws + F;        // [N,256] (aliased: z-buffer, dual1 output)
    float* agg  = ws + 2 * F;    // [N,256] (aliased: r*h buffer, then W_dec^T)
    float* nxt  = ws + 3 * F;    // [N,256]
    float* wbuf = ws + 4 * F;    // [E] softmax weights (original edge order)
    float* wp   = wbuf + N_EDGES;          // [E] dst-sorted weights
    int*   sp   = (int*)(wp + N_EDGES);    // [E] dst-sorted src ids
    float* adjA = (float*)(sp + N_EDGES);  // [N]
    float* adjB = adjA + N_NODES;          // [N]
    float* dv   = adjB + N_NODES;          // [N]
    int*   rp_s = (int*)(dv + N_NODES);    // [N+1]
    int*   rp_d = rp_s + (N_NODES + 1);    // [N+1]
    int*   cnt  = rp_d + (N_NODES + 1);    // [N]
    float* red  = (float*)(cnt + N_NODES); // [8]
    float* zb = t;    // alias: z stored where t was (t dead after agg_kernel)
    float* rh = agg;  // alias: r*h stored where agg was (agg dead after nxt gemm)
    float* wdt = agg; // alias: W_dec^T (after all layers)

    const dim3 g_gemm(157, 4);

    zero_misc_kernel<<<40, 256, 0, stream>>>(cnt, red);
    encode_kernel<<<N_NODES, 256, 0, stream>>>(feat, emb, W_enc, b_enc, h);
    rowptr_kernel<<<40, 256, 0, stream>>>(e_src, rp_s);

    for (int L = 0; L < 3; ++L) {
        gemm_epi<EPI_NONE, false><<<g_gemm, 256, 0, stream>>>(h, W_ai, nullptr, nullptr, nullptr, nullptr, nullptr, t);
        agg_kernel<<<N_NODES, 256, 0, stream>>>(t, e_dst, rp_s, agg);
        gemm_epi<EPI_TANH, false><<<g_gemm, 256, 0, stream>>>(agg, W_ao, nullptr, nullptr, b_agg, nullptr, nullptr, nxt);
        gemm_epi<EPI_SIGM, true><<<g_gemm, 256, 0, stream>>>(nxt, W_z, h, U_z, b_z, nullptr, nullptr, zb);
        gemm_epi<EPI_RH, true><<<g_gemm, 256, 0, stream>>>(nxt, W_r, h, U_r, b_r, h, nullptr, rh);
        gemm_epi<EPI_HOUT, true><<<g_gemm, 256, 0, stream>>>(nxt, W_h, rh, U_h, b_h, h, zb, h);
    }

    transpose_kernel<<<dim3(313, 8), 256, 0, stream>>>(W_dec, wdt);
    logits_softmax_kernel<<<N_NODES, 256, 0, stream>>>(h, wdt, b_dec, e_dst, rp_s, wbuf);

    hist_kernel<<<NBLK_E, 256, 0, stream>>>(e_dst, cnt);
    scan_kernel<<<1, 256, 0, stream>>>(cnt, rp_d);
    scatter_kernel<<<NBLK_E, 256, 0, stream>>>(e_src, e_dst, wbuf, rp_d, cnt, sp, wp);

    init_adj_kernel<<<40, 256, 0, stream>>>(dem, adjA);  // adj^1 = relu(-d)
    float* aold = adjA; float* anew = adjB;
    for (int it = 0; it < 9; ++it) {                      // adj^2 .. adj^10
        flow_iter_kernel<<<2500, 256, 0, stream>>>(wp, sp, rp_d, aold, dem, anew);
        float* tmp = aold; aold = anew; anew = tmp;
    }
    flow_out_kernel<<<NBLK_E, 256, 0, stream>>>(wbuf, e_src, aold, (float*)d_out + 1, red);

    gemm_epi<EPI_RELU, false><<<g_gemm, 256, 0, stream>>>(h, W_d1, nullptr, nullptr, b_d1, nullptr, nullptr, t);
    dv_kernel<<<2500, 256, 0, stream>>>(t, W_d2, b_d2, dem, dv, red);
    dual_edge_kernel<<<NBLK_E, 256, 0, stream>>>(dv, e_src, e_dst, red);
    finalize_kernel<<<1, 1, 0, stream>>>(red, (float*)d_out);
}

// Round 8
// 1360.722 us; speedup vs baseline: 1.0205x; 1.0205x over previous
//
#include <hip/hip_runtime.h>
#include <hip/hip_bf16.h>
#include <math.h>

#define N_NODES 10000
#define N_EDGES 640000
#define DDIM 256
#define NBLK_E 2500   // N_EDGES / 256 exactly

typedef long long i64;
typedef __attribute__((ext_vector_type(8))) short short8;   // 8 bf16 carried as shorts (4 VGPRs)
typedef __attribute__((ext_vector_type(4))) float f32x4;

__device__ __forceinline__ float sigmoidf_(float x) { return 1.0f / (1.0f + expf(-x)); }
__device__ __forceinline__ short bf16_hi(float f, float& hf) {
    __hip_bfloat16 h = __float2bfloat16(f);          // RNE
    hf = __bfloat162float(h);
    return __builtin_bit_cast(short, h);
}
__device__ __forceinline__ short bf16_of(float f) {
    __hip_bfloat16 h = __float2bfloat16(f);
    return __builtin_bit_cast(short, h);
}

// ---------------- encoder: h = relu([emb|feat] @ W_enc + b_enc) ----------------
__global__ __launch_bounds__(256) void encode_kernel(
    const float* __restrict__ feat, const float* __restrict__ emb,
    const float* __restrict__ W, const float* __restrict__ b, float* __restrict__ h)
{
    const int n = blockIdx.x;
    const int t = threadIdx.x;
    __shared__ float in_s[40];
    if (t < 32) in_s[t] = emb[(i64)n * 32 + t];
    else if (t < 40) in_s[t] = feat[(i64)n * 8 + (t - 32)];
    __syncthreads();
    float acc = b[t];
#pragma unroll
    for (int k = 0; k < 40; ++k) acc += in_s[k] * W[k * DDIM + t];
    h[(i64)n * DDIM + t] = fmaxf(acc, 0.0f);
}

// ---------------- weight pre-transpose + bf16 hi/lo decompose ----------------
// Wt[c*256+k] = W[k*256+c] split into hi/lo bf16 (stored as short). 9 matrices;
// each gets 2*65536 slots (hi then lo).
struct Wsrc { const float* s[9]; };

__global__ __launch_bounds__(256) void conv_w_kernel(Wsrc wsrc, short* __restrict__ wt)
{
    const int m = blockIdx.y;
    const float* __restrict__ src = wsrc.s[m];
    short* dh = wt + (i64)m * 131072;
    short* dl = dh + 65536;
    const int e = blockIdx.x * 256 + threadIdx.x;   // 0..65535
    const int c = e >> 8, k = e & 255;
    const float f = src[k * 256 + c];               // strided read (L2), coalesced write
    float hf;
    const short hb = bf16_hi(f, hf);
    dh[(i64)c * 256 + k] = hb;
    dl[(i64)c * 256 + k] = bf16_of(f - hf);
}

// ---------------- MFMA split-bf16 GEMM: C = epi(A1@W1 [+ A2@W2] + bias) ----------------
// A: fp32 [M,256] row-major, decomposed to bf16 hi/lo in-register.
// W: pre-decomposed transposed tables Wt[col][k] (hi & lo).
// 3-term product: ah*bh + ah*bl + al*bh (al*bl ~1e-6 rel, dropped). fp32 accum.
// Block 256 thr = 4 waves; block tile 64x64; wave quadrant 32x32 = 2x2 MFMA tiles.
// mfma_f32_16x16x32_bf16: A[lane&15][8*(lane>>4)+j]; B[8*(lane>>4)+j][lane&15];
// D: col=lane&15, row=4*(lane>>4)+q (q=reg 0..3)  [m89-verified]
enum { EPI_NONE = 0, EPI_TANH, EPI_SIGM, EPI_RH, EPI_HOUT, EPI_RELU };

__device__ __forceinline__ void load_cvt_frag(const float* __restrict__ p, bool ok,
                                              short8& hi, short8& lo)
{
    f32x4 v0 = {}, v1 = {};
    if (ok) { v0 = *(const f32x4*)p; v1 = *(const f32x4*)(p + 4); }
#pragma unroll
    for (int j = 0; j < 4; ++j) {
        float h0f, h1f;
        hi[j]     = bf16_hi(v0[j], h0f);
        hi[j + 4] = bf16_hi(v1[j], h1f);
        lo[j]     = bf16_of(v0[j] - h0f);
        lo[j + 4] = bf16_of(v1[j] - h1f);
    }
}

template<int EPI, bool DUAL>
__global__ __launch_bounds__(256) void gemm_mfma(
    const float* __restrict__ A1, const short* __restrict__ W1h, const short* __restrict__ W1l,
    const float* __restrict__ A2, const short* __restrict__ W2h, const short* __restrict__ W2l,
    const float* __restrict__ bias,
    const float* __restrict__ haux, const float* __restrict__ zaux,
    float* __restrict__ C)
{
    const int tid = threadIdx.x;
    const int w = tid >> 6, lane = tid & 63;
    const int lr = lane & 15, g = lane >> 4;
    const int brow = blockIdx.x * 64 + (w >> 1) * 32;
    const int bcol = blockIdx.y * 64 + (w & 1) * 32;

    const int r0 = brow + lr, r1 = brow + 16 + lr;
    const bool ok0 = r0 < N_NODES, ok1 = r1 < N_NODES;
    const i64 wcoff0 = (i64)(bcol + lr) * 256 + 8 * g;        // B col-tile 0
    const i64 wcoff1 = (i64)(bcol + 16 + lr) * 256 + 8 * g;   // B col-tile 1

    f32x4 acc[2][2] = {};

    for (int pass = 0; pass < (DUAL ? 2 : 1); ++pass) {
        const float* __restrict__ A  = pass ? A2 : A1;
        const short* __restrict__ Wh = pass ? W2h : W1h;
        const short* __restrict__ Wl = pass ? W2l : W1l;
        const float* a0p = A + (i64)r0 * DDIM + 8 * g;
        const float* a1p = A + (i64)r1 * DDIM + 8 * g;
#pragma unroll 2
        for (int k0 = 0; k0 < DDIM; k0 += 32) {
            short8 a0h, a0l, a1h, a1l;
            load_cvt_frag(a0p + k0, ok0, a0h, a0l);
            load_cvt_frag(a1p + k0, ok1, a1h, a1l);
            short8 b0h = *(const short8*)(Wh + wcoff0 + k0);
            short8 b0l = *(const short8*)(Wl + wcoff0 + k0);
            short8 b1h = *(const short8*)(Wh + wcoff1 + k0);
            short8 b1l = *(const short8*)(Wl + wcoff1 + k0);

            acc[0][0] = __builtin_amdgcn_mfma_f32_16x16x32_bf16(a0h, b0h, acc[0][0], 0, 0, 0);
            acc[0][0] = __builtin_amdgcn_mfma_f32_16x16x32_bf16(a0h, b0l, acc[0][0], 0, 0, 0);
            acc[0][0] = __builtin_amdgcn_mfma_f32_16x16x32_bf16(a0l, b0h, acc[0][0], 0, 0, 0);

            acc[0][1] = __builtin_amdgcn_mfma_f32_16x16x32_bf16(a0h, b1h, acc[0][1], 0, 0, 0);
            acc[0][1] = __builtin_amdgcn_mfma_f32_16x16x32_bf16(a0h, b1l, acc[0][1], 0, 0, 0);
            acc[0][1] = __builtin_amdgcn_mfma_f32_16x16x32_bf16(a0l, b1h, acc[0][1], 0, 0, 0);

            acc[1][0] = __builtin_amdgcn_mfma_f32_16x16x32_bf16(a1h, b0h, acc[1][0], 0, 0, 0);
            acc[1][0] = __builtin_amdgcn_mfma_f32_16x16x32_bf16(a1h, b0l, acc[1][0], 0, 0, 0);
            acc[1][0] = __builtin_amdgcn_mfma_f32_16x16x32_bf16(a1l, b0h, acc[1][0], 0, 0, 0);

            acc[1][1] = __builtin_amdgcn_mfma_f32_16x16x32_bf16(a1h, b1h, acc[1][1], 0, 0, 0);
            acc[1][1] = __builtin_amdgcn_mfma_f32_16x16x32_bf16(a1h, b1l, acc[1][1], 0, 0, 0);
            acc[1][1] = __builtin_amdgcn_mfma_f32_16x16x32_bf16(a1l, b1h, acc[1][1], 0, 0, 0);
        }
    }

    // epilogue: lane holds D[4g+q][lr] of each 16x16 tile
#pragma unroll
    for (int ct = 0; ct < 2; ++ct) {
        const int c = bcol + ct * 16 + lr;
        float b_c = 0.0f;
        if constexpr (EPI != EPI_NONE) b_c = bias[c];
#pragma unroll
        for (int rt = 0; rt < 2; ++rt) {
#pragma unroll
            for (int q = 0; q < 4; ++q) {
                const int r = brow + rt * 16 + 4 * g + q;
                if (r < N_NODES) {
                    const i64 idx = (i64)r * DDIM + c;
                    const float v = acc[rt][ct][q];
                    float out;
                    if constexpr (EPI == EPI_NONE)      out = v;
                    else if constexpr (EPI == EPI_TANH) out = tanhf(v + b_c);
                    else if constexpr (EPI == EPI_SIGM) out = sigmoidf_(v + b_c);
                    else if constexpr (EPI == EPI_RH)   out = sigmoidf_(v + b_c) * haux[idx];
                    else if constexpr (EPI == EPI_HOUT) {
                        float cand = tanhf(v + b_c);
                        float zz = zaux[idx];
                        out = zz * haux[idx] + (1.0f - zz) * cand;
                    } else                               out = fmaxf(v + b_c, 0.0f);
                    C[idx] = out;
                }
            }
        }
    }
}

// ---------------- agg[n,:] = sum over out-edges of node n (src-sorted CSR) of t[dst[e],:] ----------------
__global__ __launch_bounds__(256) void agg_kernel(
    const float* __restrict__ t, const int* __restrict__ dst, const int* __restrict__ rp,
    float* __restrict__ agg)
{
    const int n = blockIdx.x;
    const int d = threadIdx.x;
    const int s = rp[n], e = rp[n + 1];
    float a0 = 0.f, a1 = 0.f, a2 = 0.f, a3 = 0.f;
    int i = s;
    for (; i + 4 <= e; i += 4) {
        int d0 = dst[i], d1 = dst[i+1], d2 = dst[i+2], d3 = dst[i+3];
        a0 += t[(i64)d0 * DDIM + d];
        a1 += t[(i64)d1 * DDIM + d];
        a2 += t[(i64)d2 * DDIM + d];
        a3 += t[(i64)d3 * DDIM + d];
    }
    for (; i < e; ++i) a0 += t[(i64)dst[i] * DDIM + d];
    agg[(i64)n * DDIM + d] = (a0 + a1) + (a2 + a3);
}

// ---------------- W_dec [256,N] -> wdt [N,256] ----------------
__global__ __launch_bounds__(256) void transpose_kernel(
    const float* __restrict__ Wd, float* __restrict__ wdt)
{
    __shared__ float tile[32][33];
    const int bx = blockIdx.x;  // over N
    const int by = blockIdx.y;  // over 256
    const int tx = threadIdx.x & 31, ty = threadIdx.x >> 5; // 32x8
#pragma unroll
    for (int j = 0; j < 4; ++j) {
        int k = by * 32 + ty + j * 8;
        int nc = bx * 32 + tx;
        if (nc < N_NODES) tile[ty + j * 8][tx] = Wd[(i64)k * N_NODES + nc];
    }
    __syncthreads();
#pragma unroll
    for (int j = 0; j < 4; ++j) {
        int nr = bx * 32 + ty + j * 8;
        int k = by * 32 + tx;
        if (nr < N_NODES) wdt[(i64)nr * DDIM + k] = tile[tx][ty + j * 8];
    }
}

// ---------------- per-src-node: logits (h[n]·wdt[dst]+b_dec[dst]) then segment softmax ----------------
__global__ __launch_bounds__(256) void logits_softmax_kernel(
    const float* __restrict__ h, const float* __restrict__ wdt,
    const float* __restrict__ b_dec, const int* __restrict__ dst,
    const int* __restrict__ rp, float* __restrict__ w)
{
    const int n = blockIdx.x;
    const int s = rp[n], e = rp[n + 1];
    const int tid = threadIdx.x;
    const int lane = tid & 63, wv = tid >> 6;
    __shared__ __align__(16) float hs[256];
    __shared__ float sred[8];
    hs[tid] = h[(i64)n * DDIM + tid];
    __syncthreads();
    float4 hv = ((const float4*)hs)[lane];
    for (int i = s + wv; i < e; i += 4) {   // uniform per wave
        const int dd = dst[i];
        float4 a = *(const float4*)(wdt + (i64)dd * DDIM + (lane << 2));
        float p = a.x*hv.x + a.y*hv.y + a.z*hv.z + a.w*hv.w;
#pragma unroll
        for (int o = 32; o; o >>= 1) p += __shfl_down(p, o);
        if (lane == 0) w[i] = p + b_dec[dd];
    }
    __syncthreads();
    if (e <= s) return;  // uniform per block (no divergent barrier)
    // max
    float m = -INFINITY;
    for (int i = s + tid; i < e; i += 256) m = fmaxf(m, w[i]);
#pragma unroll
    for (int o = 32; o; o >>= 1) m = fmaxf(m, __shfl_down(m, o));
    if (lane == 0) sred[wv] = m;
    __syncthreads();
    m = fmaxf(fmaxf(sred[0], sred[1]), fmaxf(sred[2], sred[3]));
    // exp + sum
    float ss = 0.f;
    for (int i = s + tid; i < e; i += 256) { float ev = expf(w[i] - m); w[i] = ev; ss += ev; }
#pragma unroll
    for (int o = 32; o; o >>= 1) ss += __shfl_down(ss, o);
    if (lane == 0) sred[4 + wv] = ss;
    __syncthreads();
    ss = (sred[4] + sred[5]) + (sred[6] + sred[7]);
    float inv = 1.0f / ss;
    for (int i = s + tid; i < e; i += 256) w[i] *= inv;
}

// ---------------- misc small kernels ----------------
__global__ void zero_misc_kernel(int* __restrict__ cnt, float* __restrict__ red) {
    int i = blockIdx.x * 256 + threadIdx.x;
    if (i < N_NODES) cnt[i] = 0;
    if (i < 8) red[i] = 0.0f;
}

__global__ void rowptr_kernel(const int* __restrict__ key, int* __restrict__ rp) {
    int n = blockIdx.x * 256 + threadIdx.x;
    if (n > N_NODES) return;
    int lo = 0, hi = N_EDGES;
    while (lo < hi) { int mid = (lo + hi) >> 1; if (key[mid] < n) lo = mid + 1; else hi = mid; }
    rp[n] = lo;
}

__global__ void hist_kernel(const int* __restrict__ dst, int* __restrict__ cnt) {
    int e = blockIdx.x * 256 + threadIdx.x;
    atomicAdd(&cnt[dst[e]], 1);
}

__global__ __launch_bounds__(256) void scan_kernel(int* __restrict__ cnt, int* __restrict__ rp) {
    __shared__ int part[256];
    const int t = threadIdx.x;
    const int chunk = (N_NODES + 255) / 256;
    int b = t * chunk, en = min(b + chunk, N_NODES);
    int s = 0;
    for (int i = b; i < en; ++i) s += cnt[i];
    part[t] = s;
    __syncthreads();
    for (int o = 1; o < 256; o <<= 1) {
        int v = (t >= o) ? part[t - o] : 0;
        __syncthreads();
        part[t] += v;
        __syncthreads();
    }
    int base = (t == 0) ? 0 : part[t - 1];
    for (int i = b; i < en; ++i) { rp[i] = base; base += cnt[i]; cnt[i] = 0; }
    if (t == 255) rp[N_NODES] = part[255];
}

__global__ void scatter_kernel(const int* __restrict__ src, const int* __restrict__ dst,
                               const float* __restrict__ w, const int* __restrict__ rp_d,
                               int* __restrict__ cnt, int* __restrict__ sp, float* __restrict__ wp)
{
    int e = blockIdx.x * 256 + threadIdx.x;
    int dd = dst[e];
    int pos = rp_d[dd] + atomicAdd(&cnt[dd], 1);
    sp[pos] = src[e];
    wp[pos] = w[e];
}

__global__ void init_adj_kernel(const float* __restrict__ dem, float* __restrict__ adjA) {
    int n = blockIdx.x * 256 + threadIdx.x;
    if (n < N_NODES) adjA[n] = fmaxf(-dem[n], 0.0f);
}

// adj_new[n] = relu( sum_{incoming edges of n} wp[i]*adj_old[sp[i]] - d[n] )
__global__ __launch_bounds__(256) void flow_iter_kernel(
    const float* __restrict__ wp, const int* __restrict__ sp, const int* __restrict__ rp_d,
    const float* __restrict__ adj_old, const float* __restrict__ dem, float* __restrict__ adj_new)
{
    const int n = blockIdx.x * 4 + (threadIdx.x >> 6);
    if (n >= N_NODES) return;
    const int lane = threadIdx.x & 63;
    const int s = rp_d[n], e = rp_d[n + 1];
    float acc = 0.f;
    for (int i = s + lane; i < e; i += 64) acc += wp[i] * adj_old[sp[i]];
#pragma unroll
    for (int o = 32; o; o >>= 1) acc += __shfl_down(acc, o);
    if (lane == 0) adj_new[n] = fmaxf(acc - dem[n], 0.0f);
}

__global__ __launch_bounds__(256) void flow_out_kernel(
    const float* __restrict__ w, const int* __restrict__ src, const float* __restrict__ adj,
    float* __restrict__ out_flow, float* __restrict__ red)
{
    __shared__ float sred[4];
    int e = blockIdx.x * 256 + threadIdx.x;
    float f = w[e] * adj[src[e]];
    out_flow[e] = f;
    float p = f * f;
#pragma unroll
    for (int o = 32; o; o >>= 1) p += __shfl_down(p, o);
    int lane = threadIdx.x & 63, wv = threadIdx.x >> 6;
    if (lane == 0) sred[wv] = p;
    __syncthreads();
    if (threadIdx.x == 0) atomicAdd(&red[0], (sred[0] + sred[1]) + (sred[2] + sred[3]));
}

// dv[n] = dual-head output; one wave per node; one atomic per block
__global__ __launch_bounds__(256) void dv_kernel(
    const float* __restrict__ t2, const float* __restrict__ Wd2, const float* __restrict__ bd2,
    const float* __restrict__ dem, float* __restrict__ dv, float* __restrict__ red)
{
    __shared__ float sred[4];
    const int n = blockIdx.x * 4 + (threadIdx.x >> 6);
    const int lane = threadIdx.x & 63, wv = threadIdx.x >> 6;
    float contrib = 0.0f;
    if (n < N_NODES) {
        float4 a = *(const float4*)(t2 + (i64)n * DDIM + (lane << 2));
        float4 b = *(const float4*)(Wd2 + (lane << 2));
        float p = a.x*b.x + a.y*b.y + a.z*b.z + a.w*b.w;
#pragma unroll
        for (int o = 32; o; o >>= 1) p += __shfl_down(p, o);
        if (lane == 0) {
            float v = p + bd2[0];
            dv[n] = v;
            contrib = v * dem[n];
        }
    }
    if (lane == 0) sred[wv] = contrib;
    __syncthreads();
    if (threadIdx.x == 0) atomicAdd(&red[2], (sred[0] + sred[1]) + (sred[2] + sred[3]));
}

__global__ __launch_bounds__(256) void dual_edge_kernel(
    const float* __restrict__ dv, const int* __restrict__ src, const int* __restrict__ dst,
    float* __restrict__ red)
{
    __shared__ float sred[4];
    int e = blockIdx.x * 256 + threadIdx.x;
    float df = dv[src[e]] - dv[dst[e]];
    float f = fmaxf(df * 0.5f, 0.0f);
    float val = f * f - f * df;
#pragma unroll
    for (int o = 32; o; o >>= 1) val += __shfl_down(val, o);
    int lane = threadIdx.x & 63, wv = threadIdx.x >> 6;
    if (lane == 0) sred[wv] = val;
    __syncthreads();
    if (threadIdx.x == 0) atomicAdd(&red[1], (sred[0] + sred[1]) + (sred[2] + sred[3]));
}

__global__ void finalize_kernel(const float* __restrict__ red, float* __restrict__ out) {
    // loss = flow_cost - dual_cost = red0 - (red1 - red2) = red0 - red1 + red2
    out[0] = red[0] - red[1] + red[2];
}

// ---------------- launch ----------------
extern "C" void kernel_launch(void* const* d_in, const int* in_sizes, int n_in,
                              void* d_out, int out_size, void* d_ws, size_t ws_size,
                              hipStream_t stream) {
    (void)in_sizes; (void)n_in; (void)out_size; (void)ws_size;
    const float* feat   = (const float*)d_in[0];
    const float* emb    = (const float*)d_in[1];
    const float* dem    = (const float*)d_in[2];
    const int*   e_src  = (const int*)d_in[3];
    const int*   e_dst  = (const int*)d_in[4];
    const float* W_enc  = (const float*)d_in[5];
    const float* b_enc  = (const float*)d_in[6];
    const float* W_ai   = (const float*)d_in[7];
    const float* W_ao   = (const float*)d_in[8];
    const float* b_agg  = (const float*)d_in[9];
    const float* W_z    = (const float*)d_in[10];
    const float* U_z    = (const float*)d_in[11];
    const float* b_z    = (const float*)d_in[12];
    const float* W_r    = (const float*)d_in[13];
    const float* U_r    = (const float*)d_in[14];
    const float* b_r    = (const float*)d_in[15];
    const float* W_h    = (const float*)d_in[16];
    const float* U_h    = (const float*)d_in[17];
    const float* b_h    = (const float*)d_in[18];
    const float* W_dec  = (const float*)d_in[19];
    const float* b_dec  = (const float*)d_in[20];
    const float* W_d1   = (const float*)d_in[21];
    const float* b_d1   = (const float*)d_in[22];
    const float* W_d2   = (const float*)d_in[23];
    const float* b_d2   = (const float*)d_in[24];

    float* ws = (float*)d_ws;
    const size_t F = (size_t)N_NODES * DDIM;
    float* h    = ws;            // [N,256] fp32
    float* t    = ws + F;        // [N,256] (aliased: z-buffer, dual1 output)
    float* agg  = ws + 2 * F;    // [N,256] (aliased: r*h buffer, then W_dec^T)
    float* nxt  = ws + 3 * F;    // [N,256]
    float* wbuf = ws + 4 * F;    // [E] softmax weights (original edge order)
    float* wp   = wbuf + N_EDGES;          // [E] dst-sorted weights
    int*   sp   = (int*)(wp + N_EDGES);    // [E] dst-sorted src ids
    float* adjA = (float*)(sp + N_EDGES);  // [N]
    float* adjB = adjA + N_NODES;          // [N]
    float* dv   = adjB + N_NODES;          // [N]
    int*   rp_s = (int*)(dv + N_NODES);    // [N+1]
    int*   rp_d = rp_s + (N_NODES + 1);    // [N+1]
    int*   cnt  = rp_d + (N_NODES + 1);    // [N]
    float* red  = (float*)(cnt + N_NODES); // [8]
    short* wt   = (short*)(red + 8);       // 9 matrices x (hi 65536 + lo 65536) bf16-as-short
    float* zb = t;    // alias: z stored where t was (t dead after agg_kernel)
    float* rh = agg;  // alias: r*h stored where agg was (agg dead after nxt gemm)
    float* wdt = agg; // alias: W_dec^T (after all layers)

    // wt table order: [W_ai, W_ao, W_z, U_z, W_r, U_r, W_h, U_h, W_d1]
    short* ai_h = wt + 0*131072; short* ai_l = ai_h + 65536;
    short* ao_h = wt + 1*131072; short* ao_l = ao_h + 65536;
    short* z_h  = wt + 2*131072; short* z_l  = z_h  + 65536;
    short* uz_h = wt + 3*131072; short* uz_l = uz_h + 65536;
    short* r_h  = wt + 4*131072; short* r_l  = r_h  + 65536;
    short* ur_h = wt + 5*131072; short* ur_l = ur_h + 65536;
    short* wh_h = wt + 6*131072; short* wh_l = wh_h + 65536;
    short* uh_h = wt + 7*131072; short* uh_l = uh_h + 65536;
    short* d1_h = wt + 8*131072; short* d1_l = d1_h + 65536;

    const dim3 g_gemm(157, 4);

    Wsrc wsrc;
    wsrc.s[0] = W_ai; wsrc.s[1] = W_ao; wsrc.s[2] = W_z; wsrc.s[3] = U_z;
    wsrc.s[4] = W_r;  wsrc.s[5] = U_r;  wsrc.s[6] = W_h; wsrc.s[7] = U_h;
    wsrc.s[8] = W_d1;

    zero_misc_kernel<<<40, 256, 0, stream>>>(cnt, red);
    conv_w_kernel<<<dim3(256, 9), 256, 0, stream>>>(wsrc, wt);
    encode_kernel<<<N_NODES, 256, 0, stream>>>(feat, emb, W_enc, b_enc, h);
    rowptr_kernel<<<40, 256, 0, stream>>>(e_src, rp_s);

    for (int L = 0; L < 3; ++L) {
        gemm_mfma<EPI_NONE, false><<<g_gemm, 256, 0, stream>>>(h, ai_h, ai_l, nullptr, nullptr, nullptr, nullptr, nullptr, nullptr, t);
        agg_kernel<<<N_NODES, 256, 0, stream>>>(t, e_dst, rp_s, agg);
        gemm_mfma<EPI_TANH, false><<<g_gemm, 256, 0, stream>>>(agg, ao_h, ao_l, nullptr, nullptr, nullptr, b_agg, nullptr, nullptr, nxt);
        gemm_mfma<EPI_SIGM, true><<<g_gemm, 256, 0, stream>>>(nxt, z_h, z_l, h, uz_h, uz_l, b_z, nullptr, nullptr, zb);
        gemm_mfma<EPI_RH, true><<<g_gemm, 256, 0, stream>>>(nxt, r_h, r_l, h, ur_h, ur_l, b_r, h, nullptr, rh);
        gemm_mfma<EPI_HOUT, true><<<g_gemm, 256, 0, stream>>>(nxt, wh_h, wh_l, rh, uh_h, uh_l, b_h, h, zb, h);
    }

    transpose_kernel<<<dim3(313, 8), 256, 0, stream>>>(W_dec, wdt);
    logits_softmax_kernel<<<N_NODES, 256, 0, stream>>>(h, wdt, b_dec, e_dst, rp_s, wbuf);

    hist_kernel<<<NBLK_E, 256, 0, stream>>>(e_dst, cnt);
    scan_kernel<<<1, 256, 0, stream>>>(cnt, rp_d);
    scatter_kernel<<<NBLK_E, 256, 0, stream>>>(e_src, e_dst, wbuf, rp_d, cnt, sp, wp);

    init_adj_kernel<<<40, 256, 0, stream>>>(dem, adjA);  // adj^1 = relu(-d)
    float* aold = adjA; float* anew = adjB;
    for (int it = 0; it < 9; ++it) {                      // adj^2 .. adj^10
        flow_iter_kernel<<<2500, 256, 0, stream>>>(wp, sp, rp_d, aold, dem, anew);
        float* tmp = aold; aold = anew; anew = tmp;
    }
    flow_out_kernel<<<NBLK_E, 256, 0, stream>>>(wbuf, e_src, aold, (float*)d_out + 1, red);

    gemm_mfma<EPI_RELU, false><<<g_gemm, 256, 0, stream>>>(h, d1_h, d1_l, nullptr, nullptr, nullptr, b_d1, nullptr, nullptr, t);
    dv_kernel<<<2500, 256, 0, stream>>>(t, W_d2, b_d2, dem, dv, red);
    dual_edge_kernel<<<NBLK_E, 256, 0, stream>>>(dv, e_src, e_dst, red);
    finalize_kernel<<<1, 1, 0, stream>>>(red, (float*)d_out);
}